// Round 3
// baseline (545.396 us; speedup 1.0000x reference)
//
#include <hip/hip_runtime.h>
#include <hip/hip_bf16.h>

// Problem constants: B=2, DIM=32, CV=HDIM=96, H=W=512, FOLD=8 -> 128 tiles of 64x64,
// S=4 superpixels/tile (P=2), NCLS=16.
// Dtypes: inputs float32, d_out float32 (packing analysis round 2), gt int32.
// Key simplifications proven from the reference:
//  - With P=2 the 9-candidate neighbor softmax is exactly a softmax over all 4 superpixels.
//  - |F|^2 cancels; score[s] = 2*F.cen_s - |cen_s|^2.
//  - df.cen_df[s] = x.(Wf^T cen_df[s]) + bf.cen_df[s]  => precompute u_df[s][32] per tile.

// ---- ws layout (float offsets) ----
#define OFF_POOLX   0          // [128][32][4]
#define OFF_POOLS   16384      // [128][31][4]
#define OFF_CENPF0  32256      // [128][96][4]
#define OFF_UDF     81408      // [128][4][32]
#define OFF_USF     97792      // [128][4][31]
#define OFF_GCONST  113664     // [128][4]
#define OFF_NORM0   114176     // [128][4]
#define OFF_NUM1    114688     // [128][96][4]  (zeroed, atomics)
#define OFF_DEN1    163840     // [128][4]      (zeroed, atomics)
#define OFF_CENPF1  164352     // [128][96][4]
#define OFF_NORM1   213504     // [128][4]
#define OFF_OUTNUM  214016     // [128][96][4]  (zeroed, atomics)
#define OFF_OUTDEN  263168     // [128][4]      (zeroed, atomics)
#define OFF_LABELS  263680     // [128][4][16]  (zeroed, atomics)
#define OFF_G       271872     // [128][4][4096]
// total = 2369024 floats = 9.5 MB

// ---- d_out layout (float elements) ----
#define OUT_CF 0        // center_feat [2][256][96]
#define OUT_LB 49152    // labels      [2][16][256]
#define OUT_SP 57344    // spix_map    [2][512][512]

__device__ __forceinline__ float bf2f(unsigned short u) {
  return __uint_as_float(((unsigned)u) << 16);
}
__device__ __forceinline__ unsigned short f2bf(float f) {
  return (unsigned short)(__float_as_uint(f) >> 16);   // truncate; ~0.4% err, tolerant path only
}

// K1: pool every channel of x/sdf/feat into per-tile 2x2 quadrant means.
// grid (159 channels, 128 tiles), 256 threads. float4 vector loads.
__global__ __launch_bounds__(256) void k_pool(const float* __restrict__ x,
    const float* __restrict__ feat, const float* __restrict__ sdf,
    float* __restrict__ ws) {
  int tile = blockIdx.y, ch = blockIdx.x, tid = threadIdx.x;
  const float* src; int c, C; float* dst;
  if (ch < 32)      { src = x;    C = 32; c = ch;      dst = ws + OFF_POOLX  + (tile*32 + c)*4; }
  else if (ch < 63) { src = sdf;  C = 31; c = ch - 32; dst = ws + OFF_POOLS  + (tile*31 + c)*4; }
  else              { src = feat; C = 96; c = ch - 63; dst = ws + OFF_CENPF0 + (tile*96 + c)*4; }
  int b = tile >> 6, tl = tile & 63, f1 = tl >> 3, f2 = tl & 7;
  const float* base = src + ((size_t)(b*C + c)*512 + f1*64)*512 + f2*64;
  float acc0 = 0.f, acc1 = 0.f;   // qy=0 / qy=1 partials; qx fixed per 8-lane group
  #pragma unroll
  for (int i = 0; i < 4; ++i) {
    int vi = i*256 + tid;
    int y = vi >> 4, xv = vi & 15;             // 16 x 16B vectors per 64px row
    const float4* p = reinterpret_cast<const float4*>(base + (size_t)y*512 + xv*4);
    float4 v = *p;
    float s4 = v.x + v.y + v.z + v.w;
    if (i < 2) acc0 += s4; else acc1 += s4;
  }
  // 8 consecutive lanes share (y, qx) -> reduce groups of 8
  acc0 += __shfl_xor(acc0, 1, 64); acc0 += __shfl_xor(acc0, 2, 64); acc0 += __shfl_xor(acc0, 4, 64);
  acc1 += __shfl_xor(acc1, 1, 64); acc1 += __shfl_xor(acc1, 2, 64); acc1 += __shfl_xor(acc1, 4, 64);
  __shared__ float part[64];   // [q][16]
  int lane = tid & 63, wave = tid >> 6;
  if ((lane & 7) == 0) {
    int g = lane >> 3, qx = g & 1, gj = g >> 1;
    part[qx*16       + wave*4 + gj] = acc0;    // q = 0*2+qx
    part[(2 + qx)*16 + wave*4 + gj] = acc1;    // q = 1*2+qx
  }
  __syncthreads();
  if (tid < 64) {
    float v = part[tid];
    v += __shfl_xor(v, 1, 64); v += __shfl_xor(v, 2, 64);
    v += __shfl_xor(v, 4, 64); v += __shfl_xor(v, 8, 64);
    if ((tid & 15) == 0) dst[tid >> 4] = v * (1.f/1024.f);
  }
}

// K2: per tile: cen_df/cen_sf from pooled x/sdf; u_df, u_sf, gconst, norm0.
__global__ __launch_bounds__(384) void k_centers(const float* __restrict__ Wf,
    const float* __restrict__ bfv, const float* __restrict__ Wsdf,
    const float* __restrict__ bsdf, float* __restrict__ ws) {
  int tile = blockIdx.x, tid = threadIdx.x;
  __shared__ float px[128];    // [32][4]
  __shared__ float ps[124];    // [31][4]
  __shared__ float cdf[384];   // [96][4]
  __shared__ float csf[384];
  __shared__ float redg[4], redn[4];
  if (tid < 128) px[tid] = ws[OFF_POOLX + tile*128 + tid];
  if (tid < 124) ps[tid] = ws[OFF_POOLS + tile*124 + tid];
  if (tid < 4) { redg[tid] = 0.f; redn[tid] = 0.f; }
  __syncthreads();
  int c = tid % 96, s = tid / 96;
  float bc = bfv[c];
  float a = bc;
  for (int k = 0; k < 32; ++k) a += Wf[c*32 + k] * px[k*4 + s];
  cdf[c*4 + s] = a;
  float bs = bsdf[c];
  float a2 = bs;
  for (int k = 0; k < 31; ++k) a2 += Wsdf[c*31 + k] * ps[k*4 + s];
  csf[c*4 + s] = a2;
  // gconst[s] = 2*(bf.cen_df + bsdf.cen_sf) - (|cen_df|^2 + |cen_sf|^2)
  atomicAdd(&redg[s], 2.f*(bc*a + bs*a2) - (a*a + a2*a2));
  float cp = ws[OFF_CENPF0 + tile*384 + c*4 + s];
  atomicAdd(&redn[s], cp*cp);
  __syncthreads();
  if (tid < 128) {                       // u_df[s][k]
    int s2 = tid >> 5, k = tid & 31;
    float u = 0.f;
    for (int c2 = 0; c2 < 96; ++c2) u += Wf[c2*32 + k] * cdf[c2*4 + s2];
    ws[OFF_UDF + tile*128 + tid] = u;
  } else if (tid < 252) {                // u_sf[s][k]
    int t2 = tid - 128, s2 = t2 / 31, k = t2 % 31;
    float u = 0.f;
    for (int c2 = 0; c2 < 96; ++c2) u += Wsdf[c2*31 + k] * csf[c2*4 + s2];
    ws[OFF_USF + tile*124 + t2] = u;
  }
  if (tid < 4) { ws[OFF_GCONST + tile*4 + tid] = redg[tid]; ws[OFF_NORM0 + tile*4 + tid] = redn[tid]; }
}

// K3: SSN iter0. 4 WGs/tile x 1024 px. Computes g[s] (cached to ws), A0 softmax,
// and accumulates updated pf centroids (two-phase LDS outer product + global atomics).
__global__ __launch_bounds__(256) void k_pass2(const float* __restrict__ x,
    const float* __restrict__ feat, const float* __restrict__ sdf,
    float* __restrict__ ws) {
  int wg = blockIdx.x, tile = wg >> 2, seg = wg & 3, tid = threadIdx.x;
  int b = tile >> 6, tl = tile & 63, f1 = tl >> 3, f2 = tl & 7;
  __shared__ float s_cpf0[384];
  __shared__ float s_udf[128];
  __shared__ float s_usf[124];
  __shared__ float s_gc[4], s_n0[4];
  __shared__ float s_A0[4][257];           // padded stride
  __shared__ unsigned short s_pf[256][98]; // bf16-truncated pixel features
  for (int i = tid; i < 384; i += 256) s_cpf0[i] = ws[OFF_CENPF0 + tile*384 + i];
  if (tid < 128) s_udf[tid] = ws[OFF_UDF + tile*128 + tid];
  if (tid < 124) s_usf[tid] = ws[OFF_USF + tile*124 + tid];
  if (tid < 4) { s_gc[tid] = ws[OFF_GCONST + tile*4 + tid]; s_n0[tid] = ws[OFF_NORM0 + tile*4 + tid]; }
  __syncthreads();
  int cA = tid % 96, sA = tid / 96;
  int cB = (tid + 256) % 96, sB = (tid + 256) / 96;
  float accA = 0.f, accB = 0.f;
  float dden[4] = {0.f, 0.f, 0.f, 0.f};
  for (int chunk = 0; chunk < 4; ++chunk) {
    int p = seg*1024 + chunk*256 + tid;
    int y = p >> 6, xx = p & 63;
    int go = (f1*64 + y)*512 + f2*64 + xx;
    float d0=0.f,d1=0.f,d2=0.f,d3=0.f;
    for (int k = 0; k < 32; ++k) {
      float v = x[(b*32 + k)*262144 + go];
      d0 += v*s_udf[k]; d1 += v*s_udf[32+k]; d2 += v*s_udf[64+k]; d3 += v*s_udf[96+k];
    }
    for (int k = 0; k < 31; ++k) {
      float v = sdf[(b*31 + k)*262144 + go];
      d0 += v*s_usf[k]; d1 += v*s_usf[31+k]; d2 += v*s_usf[62+k]; d3 += v*s_usf[93+k];
    }
    float g0 = 2.f*d0 + s_gc[0], g1 = 2.f*d1 + s_gc[1];
    float g2 = 2.f*d2 + s_gc[2], g3 = 2.f*d3 + s_gc[3];
    int gbase = OFF_G + (tile << 14) + p;
    ws[gbase] = g0; ws[gbase + 4096] = g1; ws[gbase + 8192] = g2; ws[gbase + 12288] = g3;
    float p0=0.f,p1=0.f,p2=0.f,p3=0.f;
    for (int c = 0; c < 96; ++c) {
      float v = feat[(b*96 + c)*262144 + go];
      s_pf[tid][c] = f2bf(v);
      p0 += v*s_cpf0[c*4+0]; p1 += v*s_cpf0[c*4+1]; p2 += v*s_cpf0[c*4+2]; p3 += v*s_cpf0[c*4+3];
    }
    float sc0 = g0 + 2.f*p0 - s_n0[0];
    float sc1 = g1 + 2.f*p1 - s_n0[1];
    float sc2 = g2 + 2.f*p2 - s_n0[2];
    float sc3 = g3 + 2.f*p3 - s_n0[3];
    float m = fmaxf(fmaxf(sc0, sc1), fmaxf(sc2, sc3));
    float e0 = expf(sc0 - m), e1 = expf(sc1 - m), e2 = expf(sc2 - m), e3 = expf(sc3 - m);
    float inv = 1.f / (e0 + e1 + e2 + e3);
    float a0 = e0*inv, a1 = e1*inv, a2 = e2*inv, a3 = e3*inv;
    s_A0[0][tid] = a0; s_A0[1][tid] = a1; s_A0[2][tid] = a2; s_A0[3][tid] = a3;
    dden[0] += a0; dden[1] += a1; dden[2] += a2; dden[3] += a3;
    __syncthreads();
    if (tid < 128) {   // wave-uniform branch (waves 0,1 carry the 2nd accumulator)
      for (int n = 0; n < 256; ++n) {
        accA += s_A0[sA][n] * bf2f(s_pf[n][cA]);
        accB += s_A0[sB][n] * bf2f(s_pf[n][cB]);
      }
    } else {
      for (int n = 0; n < 256; ++n) accA += s_A0[sA][n] * bf2f(s_pf[n][cA]);
    }
    __syncthreads();
  }
  atomicAdd(&ws[OFF_NUM1 + (tile*96 + cA)*4 + sA], accA);
  if (tid < 128) atomicAdd(&ws[OFF_NUM1 + (tile*96 + cB)*4 + sB], accB);
  for (int m2 = 1; m2 < 64; m2 <<= 1) {
    dden[0] += __shfl_xor(dden[0], m2, 64); dden[1] += __shfl_xor(dden[1], m2, 64);
    dden[2] += __shfl_xor(dden[2], m2, 64); dden[3] += __shfl_xor(dden[3], m2, 64);
  }
  if ((tid & 63) == 0) {
    atomicAdd(&ws[OFF_DEN1 + tile*4 + 0], dden[0]);
    atomicAdd(&ws[OFF_DEN1 + tile*4 + 1], dden[1]);
    atomicAdd(&ws[OFF_DEN1 + tile*4 + 2], dden[2]);
    atomicAdd(&ws[OFF_DEN1 + tile*4 + 3], dden[3]);
  }
}

// K4: cen_pf1 = num/(den+1e-16); norm1[s] = |cen_pf1[:,s]|^2
__global__ __launch_bounds__(384) void k_fin1(float* __restrict__ ws) {
  int tile = blockIdx.x, tid = threadIdx.x;
  __shared__ float red[4];
  if (tid < 4) red[tid] = 0.f;
  __syncthreads();
  int c = tid % 96, s = tid / 96;
  float den = ws[OFF_DEN1 + tile*4 + s];
  float v = ws[OFF_NUM1 + (tile*96 + c)*4 + s] / (den + 1e-16f);
  ws[OFF_CENPF1 + (tile*96 + c)*4 + s] = v;
  atomicAdd(&red[s], v*v);
  __syncthreads();
  if (tid < 4) ws[OFF_NORM1 + tile*4 + tid] = red[tid];
}

// K5: SSN iter1: final scores from cached g + updated centroids; hard argmax,
// sim value, out accumulators, gt histogram, spix_map write.
__global__ __launch_bounds__(256) void k_pass3(const float* __restrict__ feat,
    const int* __restrict__ gt, float* __restrict__ ws, float* __restrict__ out) {
  int wg = blockIdx.x, tile = wg >> 2, seg = wg & 3, tid = threadIdx.x;
  int b = tile >> 6, tl = tile & 63, f1 = tl >> 3, f2 = tl & 7;
  __shared__ float s_cpf1[384];
  __shared__ float s_n1[4];
  __shared__ float s_W[4][257];
  __shared__ unsigned short s_pf[256][98];
  __shared__ float s_hist[64];
  for (int i = tid; i < 384; i += 256) s_cpf1[i] = ws[OFF_CENPF1 + tile*384 + i];
  if (tid < 4) s_n1[tid] = ws[OFF_NORM1 + tile*4 + tid];
  if (tid < 64) s_hist[tid] = 0.f;
  __syncthreads();
  int cA = tid % 96, sA = tid / 96;
  int cB = (tid + 256) % 96, sB = (tid + 256) / 96;
  float accA = 0.f, accB = 0.f;
  float oden[4] = {0.f, 0.f, 0.f, 0.f};
  for (int chunk = 0; chunk < 4; ++chunk) {
    int p = seg*1024 + chunk*256 + tid;
    int y = p >> 6, xx = p & 63;
    int go = (f1*64 + y)*512 + f2*64 + xx;
    int gbase = OFF_G + (tile << 14) + p;
    float g0 = ws[gbase], g1 = ws[gbase + 4096], g2 = ws[gbase + 8192], g3 = ws[gbase + 12288];
    float p0=0.f,p1=0.f,p2=0.f,p3=0.f;
    for (int c = 0; c < 96; ++c) {
      float v = feat[(b*96 + c)*262144 + go];
      s_pf[tid][c] = f2bf(v);
      p0 += v*s_cpf1[c*4+0]; p1 += v*s_cpf1[c*4+1]; p2 += v*s_cpf1[c*4+2]; p3 += v*s_cpf1[c*4+3];
    }
    float sc0 = g0 + 2.f*p0 - s_n1[0];
    float sc1 = g1 + 2.f*p1 - s_n1[1];
    float sc2 = g2 + 2.f*p2 - s_n1[2];
    float sc3 = g3 + 2.f*p3 - s_n1[3];
    int ss = 0; float best = sc0;
    if (sc1 > best) { best = sc1; ss = 1; }
    if (sc2 > best) { best = sc2; ss = 2; }
    if (sc3 > best) { best = sc3; ss = 3; }
    float se = expf(sc0-best) + expf(sc1-best) + expf(sc2-best) + expf(sc3-best);
    float sim = 1.f / se;   // softmax value at the argmax
    s_W[0][tid] = (ss == 0) ? sim : 0.f;
    s_W[1][tid] = (ss == 1) ? sim : 0.f;
    s_W[2][tid] = (ss == 2) ? sim : 0.f;
    s_W[3][tid] = (ss == 3) ? sim : 0.f;
    oden[ss] += sim;
    int gv = gt[b*262144 + go];
    atomicAdd(&s_hist[ss*16 + gv], 1.f);
    out[OUT_SP + b*262144 + go] = (float)(tl*4 + ss);
    __syncthreads();
    if (tid < 128) {
      for (int n = 0; n < 256; ++n) {
        accA += s_W[sA][n] * bf2f(s_pf[n][cA]);
        accB += s_W[sB][n] * bf2f(s_pf[n][cB]);
      }
    } else {
      for (int n = 0; n < 256; ++n) accA += s_W[sA][n] * bf2f(s_pf[n][cA]);
    }
    __syncthreads();
  }
  atomicAdd(&ws[OFF_OUTNUM + (tile*96 + cA)*4 + sA], accA);
  if (tid < 128) atomicAdd(&ws[OFF_OUTNUM + (tile*96 + cB)*4 + sB], accB);
  for (int m2 = 1; m2 < 64; m2 <<= 1) {
    oden[0] += __shfl_xor(oden[0], m2, 64); oden[1] += __shfl_xor(oden[1], m2, 64);
    oden[2] += __shfl_xor(oden[2], m2, 64); oden[3] += __shfl_xor(oden[3], m2, 64);
  }
  if ((tid & 63) == 0) {
    atomicAdd(&ws[OFF_OUTDEN + tile*4 + 0], oden[0]);
    atomicAdd(&ws[OFF_OUTDEN + tile*4 + 1], oden[1]);
    atomicAdd(&ws[OFF_OUTDEN + tile*4 + 2], oden[2]);
    atomicAdd(&ws[OFF_OUTDEN + tile*4 + 3], oden[3]);
  }
  if (tid < 64) atomicAdd(&ws[OFF_LABELS + tile*64 + tid], s_hist[tid]);
}

// K6: epilogue -> center_feat and labels
__global__ __launch_bounds__(384) void k_out(const float* __restrict__ ws,
                                             float* __restrict__ out) {
  int tile = blockIdx.x, tid = threadIdx.x;
  int b = tile >> 6, tl = tile & 63;
  int c = tid % 96, s = tid / 96;
  float od = ws[OFF_OUTDEN + tile*4 + s];
  float v = (ws[OFF_OUTNUM + (tile*96 + c)*4 + s] + ws[OFF_CENPF0 + (tile*96 + c)*4 + s]) / (od + 1.f);
  out[OUT_CF + (size_t)(b*256 + tl*4 + s)*96 + c] = v;
  if (tid < 64) {
    int s2 = tid >> 4, cls = tid & 15;
    float cnt = ws[OFF_LABELS + tile*64 + tid];
    out[OUT_LB + (b*16 + cls)*256 + tl*4 + s2] = cnt;
  }
}

extern "C" void kernel_launch(void* const* d_in, const int* in_sizes, int n_in,
                              void* d_out, int out_size, void* d_ws, size_t ws_size,
                              hipStream_t stream) {
  const float* x    = (const float*)d_in[0];
  const float* feat = (const float*)d_in[1];
  const float* sdf  = (const float*)d_in[2];
  const float* Wf   = (const float*)d_in[3];
  const float* bfv  = (const float*)d_in[4];
  const float* Wsdf = (const float*)d_in[5];
  const float* bsdf = (const float*)d_in[6];
  const int* gt = (const int*)d_in[7];
  float* ws = (float*)d_ws;
  float* out = (float*)d_out;

  // zero the atomic accumulator span (NUM1 .. LABELS end)
  hipMemsetAsync(ws + OFF_NUM1, 0,
                 (size_t)(OFF_LABELS + 128*64 - OFF_NUM1) * sizeof(float), stream);

  k_pool   <<<dim3(159, 128), 256, 0, stream>>>(x, feat, sdf, ws);
  k_centers<<<128, 384, 0, stream>>>(Wf, bfv, Wsdf, bsdf, ws);
  k_pass2  <<<512, 256, 0, stream>>>(x, feat, sdf, ws);
  k_fin1   <<<128, 384, 0, stream>>>(ws);
  k_pass3  <<<512, 256, 0, stream>>>(feat, gt, ws, out);
  k_out    <<<128, 384, 0, stream>>>(ws, out);
}

// Round 4
// 520.340 us; speedup vs baseline: 1.0482x; 1.0482x over previous
//
#include <hip/hip_runtime.h>
#include <hip/hip_bf16.h>

// B=2, DIM=32, CV=HDIM=96, H=W=512, FOLD=8 -> 128 tiles of 64x64, S=4 (P=2), NCLS=16.
// Inputs f32, output f32, gt int32.
// Simplifications: P=2 -> softmax over all 4 superpixels; |F|^2 cancels;
// conv1x1 hoisted: df.cen_df[s] = x.(Wf^T cen_df[s]) + bf.cen_df[s] -> u_df[s][32]/tile.

// ---- ws layout (float offsets) ----
#define OFF_POOLX   0          // [128][32][4]
#define OFF_POOLS   16384      // [128][31][4]
#define OFF_CENPF0  32256      // [128][96][4]
#define OFF_UDF     81408      // [128][4][32]
#define OFF_USF     97792      // [128][4][31]
#define OFF_GCONST  113664     // [128][4]
#define OFF_NORM0   114176     // [128][4]
#define OFF_NUM1    114688     // [128][96][4]  (zeroed, atomics)
#define OFF_DEN1    163840     // [128][4]      (zeroed, atomics)
#define OFF_CENPF1  164352     // [128][96][4]
#define OFF_NORM1   213504     // [128][4]
#define OFF_OUTNUM  214016     // [128][96][4]  (zeroed, atomics)
#define OFF_OUTDEN  263168     // [128][4]      (zeroed, atomics)
#define OFF_LABELS  263680     // [128][4][16]  (zeroed, atomics)
#define OFF_G       271872     // [128][4][4096]

// ---- d_out layout (float elements) ----
#define OUT_CF 0        // center_feat [2][256][96]
#define OUT_LB 49152    // labels      [2][16][256]
#define OUT_SP 57344    // spix_map    [2][512][512]

typedef float f32x4 __attribute__((ext_vector_type(4)));
typedef short bf16x8 __attribute__((ext_vector_type(8)));

__device__ __forceinline__ float bf2f(unsigned short u) {
  return __uint_as_float(((unsigned)u) << 16);
}
__device__ __forceinline__ unsigned short f2bf(float f) {
  return (unsigned short)(__float_as_uint(f) >> 16);   // truncate; tolerant paths only
}

// K1 v2: block per (plane 0..317, f1 band 0..7): reads 64 rows x 512 cols (128 KB),
// writes 8 tiles x 4 quadrant means. 256 threads: half=tid>>7 (row parity), col4=tid&127.
__global__ __launch_bounds__(256) void k_pool(const float* __restrict__ x,
    const float* __restrict__ feat, const float* __restrict__ sdf,
    float* __restrict__ ws) {
  int plane = blockIdx.x, f1 = blockIdx.y, tid = threadIdx.x;
  int b = plane / 159, ch = plane % 159;
  const float* src; int c, C, cls;
  if (ch < 32)      { src = x;    C = 32; c = ch;      cls = 0; }
  else if (ch < 63) { src = sdf;  C = 31; c = ch - 32; cls = 1; }
  else              { src = feat; C = 96; c = ch - 63; cls = 2; }
  const float* base = src + ((size_t)(b*C + c)*512 + f1*64)*512;
  int half = tid >> 7, col4 = tid & 127;
  float acc0 = 0.f, acc1 = 0.f;    // qy=0 / qy=1
  #pragma unroll 4
  for (int i = 0; i < 32; ++i) {
    int y = 2*i + half;
    float4 v = *reinterpret_cast<const float4*>(base + (size_t)y*512 + col4*4);
    float s4 = v.x + v.y + v.z + v.w;
    if (i < 16) acc0 += s4; else acc1 += s4;
  }
  // 8 consecutive lanes share (f2,qx)
  acc0 += __shfl_xor(acc0, 1, 64); acc0 += __shfl_xor(acc0, 2, 64); acc0 += __shfl_xor(acc0, 4, 64);
  acc1 += __shfl_xor(acc1, 1, 64); acc1 += __shfl_xor(acc1, 2, 64); acc1 += __shfl_xor(acc1, 4, 64);
  __shared__ float part[32][2];    // [(f2*2+qx)*2+qy][half]
  int lane = tid & 63;
  if ((lane & 7) == 0) {
    int f2 = col4 >> 4, qx = (col4 >> 3) & 1;
    part[(f2*2 + qx)*2 + 0][half] = acc0;
    part[(f2*2 + qx)*2 + 1][half] = acc1;
  }
  __syncthreads();
  if (tid < 32) {
    float v = (part[tid][0] + part[tid][1]) * (1.f/1024.f);
    int f2 = tid >> 2, qx = (tid >> 1) & 1, qy = tid & 1;
    int tile = b*64 + f1*8 + f2, s = qy*2 + qx;
    float* dst;
    if (cls == 0)      dst = ws + OFF_POOLX  + (tile*32 + c)*4;
    else if (cls == 1) dst = ws + OFF_POOLS  + (tile*31 + c)*4;
    else               dst = ws + OFF_CENPF0 + (tile*96 + c)*4;
    dst[s] = v;
  }
}

// K2: per tile: cen_df/cen_sf from pooled x/sdf; u_df, u_sf, gconst, norm0.
__global__ __launch_bounds__(384) void k_centers(const float* __restrict__ Wf,
    const float* __restrict__ bfv, const float* __restrict__ Wsdf,
    const float* __restrict__ bsdf, float* __restrict__ ws) {
  int tile = blockIdx.x, tid = threadIdx.x;
  __shared__ float px[128];
  __shared__ float ps[124];
  __shared__ float cdf[384];
  __shared__ float csf[384];
  __shared__ float redg[4], redn[4];
  if (tid < 128) px[tid] = ws[OFF_POOLX + tile*128 + tid];
  if (tid < 124) ps[tid] = ws[OFF_POOLS + tile*124 + tid];
  if (tid < 4) { redg[tid] = 0.f; redn[tid] = 0.f; }
  __syncthreads();
  int c = tid % 96, s = tid / 96;
  float bc = bfv[c];
  float a = bc;
  for (int k = 0; k < 32; ++k) a += Wf[c*32 + k] * px[k*4 + s];
  cdf[c*4 + s] = a;
  float bs = bsdf[c];
  float a2 = bs;
  for (int k = 0; k < 31; ++k) a2 += Wsdf[c*31 + k] * ps[k*4 + s];
  csf[c*4 + s] = a2;
  atomicAdd(&redg[s], 2.f*(bc*a + bs*a2) - (a*a + a2*a2));
  float cp = ws[OFF_CENPF0 + tile*384 + c*4 + s];
  atomicAdd(&redn[s], cp*cp);
  __syncthreads();
  if (tid < 128) {
    int s2 = tid >> 5, k = tid & 31;
    float u = 0.f;
    for (int c2 = 0; c2 < 96; ++c2) u += Wf[c2*32 + k] * cdf[c2*4 + s2];
    ws[OFF_UDF + tile*128 + tid] = u;
  } else if (tid < 252) {
    int t2 = tid - 128, s2 = t2 / 31, k = t2 % 31;
    float u = 0.f;
    for (int c2 = 0; c2 < 96; ++c2) u += Wsdf[c2*31 + k] * csf[c2*4 + s2];
    ws[OFF_USF + tile*124 + t2] = u;
  }
  if (tid < 4) { ws[OFF_GCONST + tile*4 + tid] = redg[tid]; ws[OFF_NORM0 + tile*4 + tid] = redn[tid]; }
}

// K3: SSN iter0. 4 WGs/tile x 1024 px. Scores f32, g cached to ws; centroid update
// via MFMA: num1[96][4] += pf[96][256px] * A0[256px][4] per chunk.
__global__ __launch_bounds__(256) void k_pass2(const float* __restrict__ x,
    const float* __restrict__ feat, const float* __restrict__ sdf,
    float* __restrict__ ws) {
  int wg = blockIdx.x, tile = wg >> 2, seg = wg & 3, tid = threadIdx.x;
  int b = tile >> 6, tl = tile & 63, f1 = tl >> 3, f2 = tl & 7;
  __shared__ float s_cpf0[384];
  __shared__ float s_udf[128];
  __shared__ float s_usf[124];
  __shared__ float s_gc[4], s_n0[4];
  __shared__ __align__(16) unsigned short s_pfT[96][264];  // [c][px] bf16
  __shared__ __align__(16) unsigned short s_aT[16][264];   // [n][px] bf16; rows 4..15 zero
  for (int i = tid; i < 384; i += 256) s_cpf0[i] = ws[OFF_CENPF0 + tile*384 + i];
  if (tid < 128) s_udf[tid] = ws[OFF_UDF + tile*128 + tid];
  if (tid < 124) s_usf[tid] = ws[OFF_USF + tile*124 + tid];
  if (tid < 4) { s_gc[tid] = ws[OFF_GCONST + tile*4 + tid]; s_n0[tid] = ws[OFF_NORM0 + tile*4 + tid]; }
  for (int i = tid; i < 16*264; i += 256) (&s_aT[0][0])[i] = 0;
  __syncthreads();
  int lane = tid & 63, wave = tid >> 6;
  int mrow = lane & 15, quad = lane >> 4;
  f32x4 zero4 = {0.f, 0.f, 0.f, 0.f};
  f32x4 accC[6] = {zero4, zero4, zero4, zero4, zero4, zero4};
  float dden[4] = {0.f, 0.f, 0.f, 0.f};
  for (int chunk = 0; chunk < 4; ++chunk) {
    int p = seg*1024 + chunk*256 + tid;
    int y = p >> 6, xx = p & 63;
    int go = (f1*64 + y)*512 + f2*64 + xx;
    float d0=0.f,d1=0.f,d2=0.f,d3=0.f;
    for (int k = 0; k < 32; ++k) {
      float v = x[(b*32 + k)*262144 + go];
      d0 += v*s_udf[k]; d1 += v*s_udf[32+k]; d2 += v*s_udf[64+k]; d3 += v*s_udf[96+k];
    }
    for (int k = 0; k < 31; ++k) {
      float v = sdf[(b*31 + k)*262144 + go];
      d0 += v*s_usf[k]; d1 += v*s_usf[31+k]; d2 += v*s_usf[62+k]; d3 += v*s_usf[93+k];
    }
    float g0 = 2.f*d0 + s_gc[0], g1 = 2.f*d1 + s_gc[1];
    float g2 = 2.f*d2 + s_gc[2], g3 = 2.f*d3 + s_gc[3];
    int gbase = OFF_G + (tile << 14) + p;
    ws[gbase] = g0; ws[gbase + 4096] = g1; ws[gbase + 8192] = g2; ws[gbase + 12288] = g3;
    float p0=0.f,p1=0.f,p2=0.f,p3=0.f;
    for (int cc = 0; cc < 96; ++cc) {
      float v = feat[(b*96 + cc)*262144 + go];
      s_pfT[cc][tid] = f2bf(v);
      p0 += v*s_cpf0[cc*4+0]; p1 += v*s_cpf0[cc*4+1]; p2 += v*s_cpf0[cc*4+2]; p3 += v*s_cpf0[cc*4+3];
    }
    float sc0 = g0 + 2.f*p0 - s_n0[0];
    float sc1 = g1 + 2.f*p1 - s_n0[1];
    float sc2 = g2 + 2.f*p2 - s_n0[2];
    float sc3 = g3 + 2.f*p3 - s_n0[3];
    float m = fmaxf(fmaxf(sc0, sc1), fmaxf(sc2, sc3));
    float e0 = expf(sc0 - m), e1 = expf(sc1 - m), e2 = expf(sc2 - m), e3 = expf(sc3 - m);
    float inv = 1.f / (e0 + e1 + e2 + e3);
    float a0 = e0*inv, a1 = e1*inv, a2 = e2*inv, a3 = e3*inv;
    s_aT[0][tid] = f2bf(a0); s_aT[1][tid] = f2bf(a1);
    s_aT[2][tid] = f2bf(a2); s_aT[3][tid] = f2bf(a3);
    dden[0] += a0; dden[1] += a1; dden[2] += a2; dden[3] += a3;
    __syncthreads();
    // MFMA: wave w handles K-steps 2w, 2w+1 (32 px each)
    #pragma unroll
    for (int kk = 0; kk < 2; ++kk) {
      int k0 = (wave*2 + kk)*32 + quad*8;
      bf16x8 bfrag = *reinterpret_cast<const bf16x8*>(&s_aT[mrow][k0]);
      #pragma unroll
      for (int mt = 0; mt < 6; ++mt) {
        bf16x8 afrag = *reinterpret_cast<const bf16x8*>(&s_pfT[mt*16 + mrow][k0]);
        accC[mt] = __builtin_amdgcn_mfma_f32_16x16x32_bf16(afrag, bfrag, accC[mt], 0, 0, 0);
      }
    }
    __syncthreads();
  }
  if (mrow < 4) {     // C/D: col=lane&15 (=s), row=quad*4+reg (=c within tile)
    #pragma unroll
    for (int mt = 0; mt < 6; ++mt)
      #pragma unroll
      for (int r = 0; r < 4; ++r) {
        int c = mt*16 + quad*4 + r;
        atomicAdd(&ws[OFF_NUM1 + (tile*96 + c)*4 + mrow], accC[mt][r]);
      }
  }
  for (int m2 = 1; m2 < 64; m2 <<= 1) {
    dden[0] += __shfl_xor(dden[0], m2, 64); dden[1] += __shfl_xor(dden[1], m2, 64);
    dden[2] += __shfl_xor(dden[2], m2, 64); dden[3] += __shfl_xor(dden[3], m2, 64);
  }
  if (lane == 0) {
    atomicAdd(&ws[OFF_DEN1 + tile*4 + 0], dden[0]);
    atomicAdd(&ws[OFF_DEN1 + tile*4 + 1], dden[1]);
    atomicAdd(&ws[OFF_DEN1 + tile*4 + 2], dden[2]);
    atomicAdd(&ws[OFF_DEN1 + tile*4 + 3], dden[3]);
  }
}

// K4: cen_pf1 = num/(den+1e-16); norm1[s] = |cen_pf1[:,s]|^2
__global__ __launch_bounds__(384) void k_fin1(float* __restrict__ ws) {
  int tile = blockIdx.x, tid = threadIdx.x;
  __shared__ float red[4];
  if (tid < 4) red[tid] = 0.f;
  __syncthreads();
  int c = tid % 96, s = tid / 96;
  float den = ws[OFF_DEN1 + tile*4 + s];
  float v = ws[OFF_NUM1 + (tile*96 + c)*4 + s] / (den + 1e-16f);
  ws[OFF_CENPF1 + (tile*96 + c)*4 + s] = v;
  atomicAdd(&red[s], v*v);
  __syncthreads();
  if (tid < 4) ws[OFF_NORM1 + tile*4 + tid] = red[tid];
}

// K5: SSN iter1: final scores from cached g; hard argmax, one-hot sim; MFMA for
// out-numerators; gt histogram; spix_map.
__global__ __launch_bounds__(256) void k_pass3(const float* __restrict__ feat,
    const int* __restrict__ gt, float* __restrict__ ws, float* __restrict__ out) {
  int wg = blockIdx.x, tile = wg >> 2, seg = wg & 3, tid = threadIdx.x;
  int b = tile >> 6, tl = tile & 63, f1 = tl >> 3, f2 = tl & 7;
  __shared__ float s_cpf1[384];
  __shared__ float s_n1[4];
  __shared__ __align__(16) unsigned short s_pfT[96][264];
  __shared__ __align__(16) unsigned short s_aT[16][264];
  __shared__ float s_hist[64];
  for (int i = tid; i < 384; i += 256) s_cpf1[i] = ws[OFF_CENPF1 + tile*384 + i];
  if (tid < 4) s_n1[tid] = ws[OFF_NORM1 + tile*4 + tid];
  if (tid < 64) s_hist[tid] = 0.f;
  for (int i = tid; i < 16*264; i += 256) (&s_aT[0][0])[i] = 0;
  __syncthreads();
  int lane = tid & 63, wave = tid >> 6;
  int mrow = lane & 15, quad = lane >> 4;
  f32x4 zero4 = {0.f, 0.f, 0.f, 0.f};
  f32x4 accC[6] = {zero4, zero4, zero4, zero4, zero4, zero4};
  float oden[4] = {0.f, 0.f, 0.f, 0.f};
  for (int chunk = 0; chunk < 4; ++chunk) {
    int p = seg*1024 + chunk*256 + tid;
    int y = p >> 6, xx = p & 63;
    int go = (f1*64 + y)*512 + f2*64 + xx;
    int gbase = OFF_G + (tile << 14) + p;
    float g0 = ws[gbase], g1 = ws[gbase + 4096], g2 = ws[gbase + 8192], g3 = ws[gbase + 12288];
    float p0=0.f,p1=0.f,p2=0.f,p3=0.f;
    for (int cc = 0; cc < 96; ++cc) {
      float v = feat[(b*96 + cc)*262144 + go];
      s_pfT[cc][tid] = f2bf(v);
      p0 += v*s_cpf1[cc*4+0]; p1 += v*s_cpf1[cc*4+1]; p2 += v*s_cpf1[cc*4+2]; p3 += v*s_cpf1[cc*4+3];
    }
    float sc0 = g0 + 2.f*p0 - s_n1[0];
    float sc1 = g1 + 2.f*p1 - s_n1[1];
    float sc2 = g2 + 2.f*p2 - s_n1[2];
    float sc3 = g3 + 2.f*p3 - s_n1[3];
    int ss = 0; float best = sc0;
    if (sc1 > best) { best = sc1; ss = 1; }
    if (sc2 > best) { best = sc2; ss = 2; }
    if (sc3 > best) { best = sc3; ss = 3; }
    float se = expf(sc0-best) + expf(sc1-best) + expf(sc2-best) + expf(sc3-best);
    float sim = 1.f / se;
    unsigned short sb = f2bf(sim);
    s_aT[0][tid] = (ss == 0) ? sb : (unsigned short)0;
    s_aT[1][tid] = (ss == 1) ? sb : (unsigned short)0;
    s_aT[2][tid] = (ss == 2) ? sb : (unsigned short)0;
    s_aT[3][tid] = (ss == 3) ? sb : (unsigned short)0;
    oden[ss] += sim;
    int gv = gt[b*262144 + go];
    atomicAdd(&s_hist[ss*16 + gv], 1.f);
    out[OUT_SP + b*262144 + go] = (float)(tl*4 + ss);
    __syncthreads();
    #pragma unroll
    for (int kk = 0; kk < 2; ++kk) {
      int k0 = (wave*2 + kk)*32 + quad*8;
      bf16x8 bfrag = *reinterpret_cast<const bf16x8*>(&s_aT[mrow][k0]);
      #pragma unroll
      for (int mt = 0; mt < 6; ++mt) {
        bf16x8 afrag = *reinterpret_cast<const bf16x8*>(&s_pfT[mt*16 + mrow][k0]);
        accC[mt] = __builtin_amdgcn_mfma_f32_16x16x32_bf16(afrag, bfrag, accC[mt], 0, 0, 0);
      }
    }
    __syncthreads();
  }
  if (mrow < 4) {
    #pragma unroll
    for (int mt = 0; mt < 6; ++mt)
      #pragma unroll
      for (int r = 0; r < 4; ++r) {
        int c = mt*16 + quad*4 + r;
        atomicAdd(&ws[OFF_OUTNUM + (tile*96 + c)*4 + mrow], accC[mt][r]);
      }
  }
  for (int m2 = 1; m2 < 64; m2 <<= 1) {
    oden[0] += __shfl_xor(oden[0], m2, 64); oden[1] += __shfl_xor(oden[1], m2, 64);
    oden[2] += __shfl_xor(oden[2], m2, 64); oden[3] += __shfl_xor(oden[3], m2, 64);
  }
  if (lane == 0) {
    atomicAdd(&ws[OFF_OUTDEN + tile*4 + 0], oden[0]);
    atomicAdd(&ws[OFF_OUTDEN + tile*4 + 1], oden[1]);
    atomicAdd(&ws[OFF_OUTDEN + tile*4 + 2], oden[2]);
    atomicAdd(&ws[OFF_OUTDEN + tile*4 + 3], oden[3]);
  }
  if (tid < 64) atomicAdd(&ws[OFF_LABELS + tile*64 + tid], s_hist[tid]);
}

// K6: epilogue -> center_feat and labels
__global__ __launch_bounds__(384) void k_out(const float* __restrict__ ws,
                                             float* __restrict__ out) {
  int tile = blockIdx.x, tid = threadIdx.x;
  int b = tile >> 6, tl = tile & 63;
  int c = tid % 96, s = tid / 96;
  float od = ws[OFF_OUTDEN + tile*4 + s];
  float v = (ws[OFF_OUTNUM + (tile*96 + c)*4 + s] + ws[OFF_CENPF0 + (tile*96 + c)*4 + s]) / (od + 1.f);
  out[OUT_CF + (size_t)(b*256 + tl*4 + s)*96 + c] = v;
  if (tid < 64) {
    int s2 = tid >> 4, cls = tid & 15;
    float cnt = ws[OFF_LABELS + tile*64 + tid];
    out[OUT_LB + (b*16 + cls)*256 + tl*4 + s2] = cnt;
  }
}

extern "C" void kernel_launch(void* const* d_in, const int* in_sizes, int n_in,
                              void* d_out, int out_size, void* d_ws, size_t ws_size,
                              hipStream_t stream) {
  const float* x    = (const float*)d_in[0];
  const float* feat = (const float*)d_in[1];
  const float* sdf  = (const float*)d_in[2];
  const float* Wf   = (const float*)d_in[3];
  const float* bfv  = (const float*)d_in[4];
  const float* Wsdf = (const float*)d_in[5];
  const float* bsdf = (const float*)d_in[6];
  const int* gt = (const int*)d_in[7];
  float* ws = (float*)d_ws;
  float* out = (float*)d_out;

  hipMemsetAsync(ws + OFF_NUM1, 0,
                 (size_t)(OFF_LABELS + 128*64 - OFF_NUM1) * sizeof(float), stream);

  k_pool   <<<dim3(318, 8), 256, 0, stream>>>(x, feat, sdf, ws);
  k_centers<<<128, 384, 0, stream>>>(Wf, bfv, Wsdf, bsdf, ws);
  k_pass2  <<<512, 256, 0, stream>>>(x, feat, sdf, ws);
  k_fin1   <<<128, 384, 0, stream>>>(ws);
  k_pass3  <<<512, 256, 0, stream>>>(feat, gt, ws, out);
  k_out    <<<128, 384, 0, stream>>>(ws, out);
}